// Round 18
// baseline (44.303 us; speedup 1.0000x reference)
//
#include <hip/hip_runtime.h>
#include <hip/hip_bf16.h>

// ANI-1 per-species MLP, v18: m97-canonical — BOTH operands glds-staged.
// Accounting from v17 counters: B-frags re-read from L2 per consuming wave
// (368KB/block = 377MB total = ~11us L2 BW), serialized at VGPR=32 (acc24+
// ah8 = zero loads in flight). Fix: B0 staged per K=64 tile (20KB, tile-major
// prep layout), B1/B2 staged whole (40/24KB), all via global_load_lds (0 VGPR,
// 0 VALU), consumed as linear conflict-free ds_read_b128 -> inner loop is
// all-LDS, compiler emits counted lgkmcnt interleave (m97-proven).
// L2 B-traffic halved; LDS phase-aliased to exactly 72KB -> 2 blocks/CU.
// Block = 512 thr (8 waves: 2 M-grp x 4 N-grp), grid = 1024 (atom, half).

typedef float f32x4 __attribute__((ext_vector_type(4)));
typedef short s16x8 __attribute__((ext_vector_type(8)));

#define NMOL   128
#define NATOM  512
#define AEV    384
#define MT     64               // molecules per block
#define Y0LD   168
#define Y1LD   136
#define Y2LD   104

// Wp element offsets (bf16 units)
#define PL0    61440            // 160*384 (tile-major: 6 tiles x 10240)
#define PL1    20480            // 128*160
#define PL2    12288            // 96*128
#define BASE0  0
#define BASE1  245760           // 4*PL0
#define BASE2  327680           // BASE1 + 4*PL1
#define WP_BYTE_OFF 262144      // partial buffer (512*128*4) first in d_ws

typedef const __attribute__((address_space(1))) void* gas_ptr;
typedef __attribute__((address_space(3))) void* las_ptr;

__device__ __forceinline__ ushort f2bf(float f) {   // RTN-even
    uint u = __float_as_uint(f);
    return (ushort)((u + 0x7fffu + ((u >> 16) & 1u)) >> 16);
}
__device__ __forceinline__ float bf2f(ushort h) {
    return __uint_as_float(((uint)h) << 16);
}
__device__ __forceinline__ float celu_f(float v) {
    return fmaxf(v, 0.0f) + fminf(0.1f * (__expf(10.0f * v) - 1.0f), 0.0f);
}
__device__ __forceinline__ uint pk2bf(float x, float y) {   // v_cvt_pk_bf16_f32
    __hip_bfloat162 h2;
    h2.x = __float2bfloat16(x);
    h2.y = __float2bfloat16(y);
    return *(uint*)&h2;
}

// ---- prep: W0..W2 fp32 -> bf16 frag order; W0 TILE-MAJOR (20KB K=64 slices)
__global__ __launch_bounds__(256) void prep_kernel(
    const float* __restrict__ W0, const float* __restrict__ W1,
    const float* __restrict__ W2, ushort* __restrict__ Wp)
{
    const int idx = blockIdx.x * 256 + threadIdx.x;   // grid = 47104 (x8 elems)
    size_t fo, base;
    const float* src;
    if (idx < 30720) {                        // L0: [4][160][384]
        const int s = idx / 7680, r = idx % 7680;
        const int n = r / 48, k0 = (r % 48) * 8;
        const int t = k0 >> 6, h = (k0 >> 5) & 1;
        fo = (size_t)t * 10240 + ((n >> 4) * 2 + h) * 512
           + (((k0 & 31) >> 3) * 16 + (n & 15)) * 8;
        src = W0 + (size_t)idx * 8;
        base = BASE0 + (size_t)s * PL0;
    } else if (idx < 40960) {                 // L1: [4][128][160]
        const int i2 = idx - 30720;
        const int s = i2 / 2560, r = i2 % 2560;
        const int n = r / 20, k0 = (r % 20) * 8;
        fo = (size_t)(((n >> 4) * 5 + (k0 >> 5)) * 64
           + ((k0 & 31) >> 3) * 16 + (n & 15)) * 8;
        src = W1 + (size_t)i2 * 8;
        base = BASE1 + (size_t)s * PL1;
    } else {                                  // L2: [4][96][128]
        const int i2 = idx - 40960;
        const int s = i2 / 1536, r = i2 % 1536;
        const int n = r / 16, k0 = (r % 16) * 8;
        fo = (size_t)(((n >> 4) * 4 + (k0 >> 5)) * 64
           + ((k0 & 31) >> 3) * 16 + (n & 15)) * 8;
        src = W2 + (size_t)i2 * 8;
        base = BASE2 + (size_t)s * PL2;
    }
    const float4 v0 = *(const float4*)(src);
    const float4 v1 = *(const float4*)(src + 4);
    uint4 w;
    w.x = pk2bf(v0.x, v0.y);
    w.y = pk2bf(v0.z, v0.w);
    w.z = pk2bf(v1.x, v1.y);
    w.w = pk2bf(v1.z, v1.w);
    *(uint4*)(Wp + base + fo) = w;
}

__global__ __attribute__((amdgpu_flat_work_group_size(512, 512),
                          amdgpu_waves_per_eu(4, 4)))
void ani_mfma_kernel(
    const float* __restrict__ aev, const int* __restrict__ species,
    const ushort* __restrict__ Wp,
    const float* __restrict__ b0, const float* __restrict__ b1,
    const float* __restrict__ b2,
    const float* __restrict__ W3, const float* __restrict__ b3,
    float* __restrict__ partial)
{
    // 73728 B, phase-aliased:
    //  L0:   A fp32 dbuf [0,32768)   B0 tile dbuf [32768,73728)
    //  L1:   Y0 [0,21504)            B1 [32768,73728)
    //  L2:   Y1 [0,17408)            B2 [32768,57344)   Y2 [17408,30720)
    //  L3:   red [0,2048)
    __shared__ __align__(16) char smem8[73728];
    ushort* smem_u = (ushort*)smem8;

    const int bid  = blockIdx.x;
    const int a    = bid >> 1;          // atom
    const int half = bid & 1;           // molecule half
    const int tid  = threadIdx.x;
    const int lane = tid & 63;
    const int wid  = tid >> 6;
    const int mgrp = wid >> 2;          // 0..1 (32-row groups)
    const int ngrp = wid & 3;           // 0..3
    const bool has3 = (ngrp < 2);       // L0 nf=ngrp+8<10; L2 nf=ngrp+4<6

    const int s = species[a];
    const ushort* Bh0 = Wp + BASE0 + (size_t)s * PL0;
    const ushort* Bh1 = Wp + BASE1 + (size_t)s * PL1;
    const ushort* Bh2 = Wp + BASE2 + (size_t)s * PL2;
    const float* b0s = b0 + s * 160;
    const float* b1s = b1 + s * 128;
    const float* b2s = b2 + s * 96;
    const float* w3s = W3 + s * 96;
    const float  bb3 = b3[s];

    ushort* y0buf = smem_u;             // [64][168]
    ushort* y1buf = smem_u;             // [64][136] (over dead Y0)
    ushort* y2buf = smem_u + 8704;      // [64][104] @ byte 17408
    const ushort* BL = smem_u + 16384;  // B region @ byte 32768

    // ---- A glds source (v17 swizzle): wave stages rows wid*8..+7 ----
    const int mol8 = lane >> 3;
    const int swz  = (lane & 7) ^ mol8;
    const char* gsrc = (const char*)(aev
        + ((size_t)(half * MT + wid * 8 + mol8) * NATOM + a) * AEV) + swz * 16;
    const int ldsbase = wid * 2048;

    auto stage_a = [&](int t, int b) {
        const char* g = gsrc + t * 256;
        char* d = smem8 + b * 16384 + ldsbase;
        __builtin_amdgcn_global_load_lds((gas_ptr)(g),       (las_ptr)(d),        16, 0, 0);
        __builtin_amdgcn_global_load_lds((gas_ptr)(g + 128), (las_ptr)(d + 1024), 16, 0, 0);
    };
    auto stage_b = [&](const ushort* gbase, int nchunks, int ldsbyte) {
        for (int c = wid; c < nchunks; c += 8)
            __builtin_amdgcn_global_load_lds(
                (gas_ptr)((const char*)gbase + c * 1024 + lane * 16),
                (las_ptr)(smem8 + ldsbyte + c * 1024), 16, 0, 0);
    };

    const f32x4 zero = {0.f, 0.f, 0.f, 0.f};
    f32x4 acc[2][3];
    #pragma unroll
    for (int mf = 0; mf < 2; ++mf)
        #pragma unroll
        for (int ti = 0; ti < 3; ++ti) acc[mf][ti] = zero;

    // ---- L0: 384 -> 160, 6 K-64 tiles, A+B0 both glds-staged ----
    {
        const int r0 = mgrp * 32 + (lane & 15);
        const int c2 = (lane >> 4) * 2;

        stage_a(0, 0);
        stage_b(Bh0, 20, 32768);
        __syncthreads();

        #pragma unroll
        for (int tt = 0; tt < 6; ++tt) {
            if (tt < 5) {
                stage_a(tt + 1, (tt + 1) & 1);
                stage_b(Bh0 + (size_t)(tt + 1) * 10240, 20,
                        32768 + ((tt + 1) & 1) * 20480);
            }
            const float*  Xb = (const float*)(smem8 + (tt & 1) * 16384);
            const ushort* Bl = BL + (tt & 1) * 10240;
            #pragma unroll
            for (int gs = 0; gs < 2; ++gs) {
                const s16x8 bh0 = *(const s16x8*)(Bl + ((ngrp      * 2 + gs) * 512) + lane * 8);
                const s16x8 bh1 = *(const s16x8*)(Bl + (((ngrp + 4) * 2 + gs) * 512) + lane * 8);
                s16x8 bh2;
                if (has3) bh2 = *(const s16x8*)(Bl + (((ngrp + 8) * 2 + gs) * 512) + lane * 8);

                s16x8 ah[2];
                #pragma unroll
                for (int mf = 0; mf < 2; ++mf) {
                    const int r = r0 + mf * 16;
                    const float* rp = Xb + (r >> 3) * 512 + gs * 256 + (r & 7) * 32;
                    const f32x4 v0 = *(const f32x4*)(rp + (((c2    ) ^ (r & 7)) * 4));
                    const f32x4 v1 = *(const f32x4*)(rp + (((c2 + 1) ^ (r & 7)) * 4));
                    union { s16x8 v; uint u[4]; } rr;
                    rr.u[0] = pk2bf(v0.x, v0.y);
                    rr.u[1] = pk2bf(v0.z, v0.w);
                    rr.u[2] = pk2bf(v1.x, v1.y);
                    rr.u[3] = pk2bf(v1.z, v1.w);
                    ah[mf] = rr.v;
                }
                acc[0][0] = __builtin_amdgcn_mfma_f32_16x16x32_bf16(ah[0], bh0, acc[0][0], 0, 0, 0);
                acc[1][0] = __builtin_amdgcn_mfma_f32_16x16x32_bf16(ah[1], bh0, acc[1][0], 0, 0, 0);
                acc[0][1] = __builtin_amdgcn_mfma_f32_16x16x32_bf16(ah[0], bh1, acc[0][1], 0, 0, 0);
                acc[1][1] = __builtin_amdgcn_mfma_f32_16x16x32_bf16(ah[1], bh1, acc[1][1], 0, 0, 0);
                if (has3) {
                    acc[0][2] = __builtin_amdgcn_mfma_f32_16x16x32_bf16(ah[0], bh2, acc[0][2], 0, 0, 0);
                    acc[1][2] = __builtin_amdgcn_mfma_f32_16x16x32_bf16(ah[1], bh2, acc[1][2], 0, 0, 0);
                }
            }
            __syncthreads();    // publishes tile tt+1 (A and B0)
        }
    }

    // ---- L0 epilogue: issue B1 glds (B0 dead); write Y0 (A dead) ----
    stage_b(Bh1, 40, 32768);
    #pragma unroll
    for (int ti = 0; ti < 3; ++ti) {
        if (ti < 2 || has3) {
            const int n = (ngrp + 4 * ti) * 16 + (lane & 15);
            const float bv = b0s[n];
            #pragma unroll
            for (int mf = 0; mf < 2; ++mf) {
                #pragma unroll
                for (int r = 0; r < 4; ++r) {
                    const int row = mgrp * 32 + mf * 16 + (lane >> 4) * 4 + r;
                    y0buf[row * Y0LD + n] = f2bf(celu_f(acc[mf][ti][r] + bv));
                }
            }
        }
    }
    __syncthreads();                    // Y0 + B1 published

    // ---- L1: 160 -> 128 (A from Y0, B from LDS) ----
    f32x4 acc1[2][2];
    #pragma unroll
    for (int mf = 0; mf < 2; ++mf) { acc1[mf][0] = zero; acc1[mf][1] = zero; }
    {
        const ushort* arow0 = y0buf + (mgrp * 32 + (lane & 15)) * Y0LD + (lane >> 4) * 8;
        #pragma unroll
        for (int ks = 0; ks < 5; ++ks) {
            s16x8 ah[2];
            ah[0] = *(const s16x8*)(arow0 + ks * 32);
            ah[1] = *(const s16x8*)(arow0 + 16 * Y0LD + ks * 32);
            const s16x8 bh0 = *(const s16x8*)(BL + ((ngrp      * 5 + ks) * 512) + lane * 8);
            const s16x8 bh1 = *(const s16x8*)(BL + (((ngrp + 4) * 5 + ks) * 512) + lane * 8);
            acc1[0][0] = __builtin_amdgcn_mfma_f32_16x16x32_bf16(ah[0], bh0, acc1[0][0], 0, 0, 0);
            acc1[1][0] = __builtin_amdgcn_mfma_f32_16x16x32_bf16(ah[1], bh0, acc1[1][0], 0, 0, 0);
            acc1[0][1] = __builtin_amdgcn_mfma_f32_16x16x32_bf16(ah[0], bh1, acc1[0][1], 0, 0, 0);
            acc1[1][1] = __builtin_amdgcn_mfma_f32_16x16x32_bf16(ah[1], bh1, acc1[1][1], 0, 0, 0);
        }
    }
    __syncthreads();                    // all Y0 + B1 reads done

    // ---- L1 epilogue: write Y1 (over Y0); issue B2 glds (over B1) ----
    stage_b(Bh2, 24, 32768);
    #pragma unroll
    for (int t = 0; t < 2; ++t) {
        const int n = (ngrp + 4 * t) * 16 + (lane & 15);
        const float bv = b1s[n];
        #pragma unroll
        for (int mf = 0; mf < 2; ++mf) {
            #pragma unroll
            for (int r = 0; r < 4; ++r) {
                const int row = mgrp * 32 + mf * 16 + (lane >> 4) * 4 + r;
                y1buf[row * Y1LD + n] = f2bf(celu_f(acc1[mf][t][r] + bv));
            }
        }
    }
    __syncthreads();                    // Y1 + B2 published

    // ---- L2: 128 -> 96 (A from Y1, B from LDS) ----
    f32x4 acc2[2][2];
    #pragma unroll
    for (int mf = 0; mf < 2; ++mf) { acc2[mf][0] = zero; acc2[mf][1] = zero; }
    {
        const ushort* arow0 = y1buf + (mgrp * 32 + (lane & 15)) * Y1LD + (lane >> 4) * 8;
        #pragma unroll
        for (int ks = 0; ks < 4; ++ks) {
            s16x8 ah[2];
            ah[0] = *(const s16x8*)(arow0 + ks * 32);
            ah[1] = *(const s16x8*)(arow0 + 16 * Y1LD + ks * 32);
            const s16x8 bh0 = *(const s16x8*)(BL + ((ngrp * 4 + ks) * 512) + lane * 8);
            acc2[0][0] = __builtin_amdgcn_mfma_f32_16x16x32_bf16(ah[0], bh0, acc2[0][0], 0, 0, 0);
            acc2[1][0] = __builtin_amdgcn_mfma_f32_16x16x32_bf16(ah[1], bh0, acc2[1][0], 0, 0, 0);
            if (has3) {
                const s16x8 bh1 = *(const s16x8*)(BL + (((ngrp + 4) * 4 + ks) * 512) + lane * 8);
                acc2[0][1] = __builtin_amdgcn_mfma_f32_16x16x32_bf16(ah[0], bh1, acc2[0][1], 0, 0, 0);
                acc2[1][1] = __builtin_amdgcn_mfma_f32_16x16x32_bf16(ah[1], bh1, acc2[1][1], 0, 0, 0);
            }
        }
    }

    // ---- L2 epilogue -> Y2 @ [17408,30720) (disjoint from Y1/B2, dead rgn) ----
    #pragma unroll
    for (int t = 0; t < 2; ++t) {
        if (t == 0 || has3) {
            const int n = (ngrp + 4 * t) * 16 + (lane & 15);   // < 96
            const float bv = b2s[n];
            #pragma unroll
            for (int mf = 0; mf < 2; ++mf) {
                #pragma unroll
                for (int r = 0; r < 4; ++r) {
                    const int row = mgrp * 32 + mf * 16 + (lane >> 4) * 4 + r;
                    y2buf[row * Y2LD + n] = f2bf(celu_f(acc2[mf][t][r] + bv));
                }
            }
        }
    }
    __syncthreads();                    // Y2 published; Y1 dead

    // ---- L3: 96 -> 1 (fp32 vector; red over dead Y1) ----
    {
        float* red = (float*)smem8;
        const int m = tid & (MT - 1);
        const int q = tid >> 6;       // 0..7, 12 inputs each
        float accv = 0.f;
        #pragma unroll
        for (int ii = 0; ii < 12; ++ii) {
            const int i = q * 12 + ii;
            accv = fmaf(w3s[i], bf2f(y2buf[m * Y2LD + i]), accv);
        }
        red[q * MT + m] = accv;
        __syncthreads();
        if (tid < MT) {
            float sm = bb3;
            #pragma unroll
            for (int qq = 0; qq < 8; ++qq) sm += red[qq * MT + tid];
            partial[(size_t)a * NMOL + half * MT + tid] = sm;
        }
    }
}

__global__ __launch_bounds__(256) void reduce_kernel(
    const float* __restrict__ partial, float* __restrict__ out)
{
    __shared__ float red[256];
    const int m = blockIdx.x;       // molecule
    const int t = threadIdx.x;
    float sv = partial[(size_t)t * NMOL + m] + partial[(size_t)(t + 256) * NMOL + m];
    red[t] = sv;
    __syncthreads();
    #pragma unroll
    for (int w = 128; w > 0; w >>= 1) {
        if (t < w) red[t] += red[t + w];
        __syncthreads();
    }
    if (t == 0) out[m] = red[0];
}

extern "C" void kernel_launch(void* const* d_in, const int* in_sizes, int n_in,
                              void* d_out, int out_size, void* d_ws, size_t ws_size,
                              hipStream_t stream) {
    const float* aev     = (const float*)d_in[0];
    const int*   species = (const int*)  d_in[1];
    const float* W0 = (const float*)d_in[2];
    const float* b0 = (const float*)d_in[3];
    const float* W1 = (const float*)d_in[4];
    const float* b1 = (const float*)d_in[5];
    const float* W2 = (const float*)d_in[6];
    const float* b2 = (const float*)d_in[7];
    const float* W3 = (const float*)d_in[8];
    const float* b3 = (const float*)d_in[9];
    float* out     = (float*)d_out;
    float* partial = (float*)d_ws;                               // 256 KiB
    ushort* Wp     = (ushort*)((char*)d_ws + WP_BYTE_OFF);       // ~0.75 MiB

    prep_kernel<<<184, 256, 0, stream>>>(W0, W1, W2, Wp);
    ani_mfma_kernel<<<NATOM * 2, 512, 0, stream>>>(aev, species, Wp,
                                                   b0, b1, b2, W3, b3, partial);
    reduce_kernel<<<NMOL, 256, 0, stream>>>(partial, out);
}